// Round 5
// baseline (33.020 us; speedup 1.0000x reference)
//
#include <hip/hip_runtime.h>

// CTC loss forward (T=512, B=1024, C=63, S=25, L=51).
// Fwd/bwd midpoint split (wave A: alpha t=0..255; wave B: beta 511..256),
// linear-domain recurrence with per-lane power-of-2 frames.
// Per step: COALESCED row load (lane i -> class i) + ds_bpermute (const idx)
// replaces the 64-lane gather that was the round-3/4 TA throughput bound.

#define TT 512
#define BB 1024
#define CC 63
#define SS 25
#define D  32
#define NEGV (-1e30f)
#define LN2F 0.69314718055994531f

__device__ __forceinline__ float shr1f(float x, float fill) {  // lane s <- x[s-1]
  return __int_as_float(__builtin_amdgcn_update_dpp(
      __float_as_int(fill), __float_as_int(x), 0x138, 0xF, 0xF, false));
}
__device__ __forceinline__ int shr1i(int x, int fill) {
  return __builtin_amdgcn_update_dpp(fill, x, 0x138, 0xF, 0xF, false);
}
__device__ __forceinline__ float shl1f(float x, float fill) {  // lane s <- x[s+1]
  return __int_as_float(__builtin_amdgcn_update_dpp(
      __float_as_int(fill), __float_as_int(x), 0x130, 0xF, 0xF, false));
}
__device__ __forceinline__ int shl1i(int x, int fill) {
  return __builtin_amdgcn_update_dpp(fill, x, 0x130, 0xF, 0xF, false);
}
__device__ __forceinline__ int iclamp126(int d) {
  return d < -126 ? -126 : (d > 126 ? 126 : d);
}

__global__ __launch_bounds__(256) void ctc_fb_kernel(
    const float* __restrict__ logp,
    const int* __restrict__ targets,
    const int* __restrict__ tlen,
    float* __restrict__ loss) {
  const int lane = threadIdx.x & 63;
  const int wid = threadIdx.x >> 6;   // 0..3
  const int pairIdx = wid >> 1;       // which batch element of this block
  const int bwd = wid & 1;
  const int b = (blockIdx.x << 1) + pairIdx;
  const int* tg = targets + b * SS;
  const int len = tlen[b];

  // ext[s]: even s -> blank(0); odd s -> tg[(s-1)/2]
  int e = 0;
  float skf = 0.0f;   // fwd: inflow s-2 -> s allowed
  float skf2 = 0.0f;  // bwd: inflow s+2 -> s allowed
  if (lane & 1) {
    const int i = lane >> 1;
    if (i < SS) {
      e = tg[i];
      skf = (i == 0 || e != tg[i - 1]) ? 1.0f : 0.0f;
      if (i + 1 < SS) skf2 = (tg[i + 1] != tg[i]) ? 1.0f : 0.0f;
    }
  }
  const int bidx = e << 2;                     // ds_bpermute byte index (constant)

  // coalesced per-lane column: lane i owns class i (lane 63 clamps to 62,
  // avoiding a 4-byte overrun on the very last row)
  const int cls = lane < (CC - 1) ? lane : (CC - 2);
  const unsigned SB = (unsigned)(BB * CC) * 4u;            // bytes per timestep
  const char* base = (const char*)logp;
  const unsigned rowoff = (unsigned)(b * CC + cls) * 4u;   // t=0 row, my class
#define LDR(O) (*(const float*)(base + (O)))
#define BPERM(X) __int_as_float(__builtin_amdgcn_ds_bpermute(bidx, __float_as_int(X)))

  __shared__ float la_s[2][64];

  float A, F1, F2m;   // F2m carries the skip mask
  int M2 = 0;
  float pf[D];        // raw row values: pf[j] holds lp[t, b, cls=lane]
  unsigned offp;

  if (!bwd) {
    // ---------- forward: alpha t=0 init, steps t=1..255 ----------
    A = (lane <= 1) ? __expf(BPERM(LDR(rowoff))) : 0.0f;
    F1 = 1.0f; F2m = skf;
    offp = rowoff + SB;
#pragma unroll
    for (int j = 0; j < D; ++j) { pf[j] = LDR(offp); offp += SB; }

#define RENF() {                                               \
    int e2 = (int)(__float_as_uint(A) >> 23) - 127;            \
    A = ldexpf(A, -e2);                                        \
    int m2n = M2 + e2;                                         \
    int m2a = shr1i(m2n, 0);                                   \
    M2 = (A == 0.0f) ? m2a : m2n;                              \
    int s1 = shr1i(M2, 0), s2 = shr1i(s1, 0);                  \
    F1 = ldexpf(1.0f, iclamp126(s1 - M2));                     \
    F2m = skf * ldexpf(1.0f, iclamp126(s2 - M2));              \
  }
#define STEPF(J, PFLAG) {                                      \
    const float P = __expf(BPERM(pf[(J)]));                    \
    const float c1 = P * F1, c2 = P * F2m;                     \
    const float a2 = shr1f(A, 0.0f);                           \
    const float pa = P * A;                                    \
    const float a3 = shr1f(a2, 0.0f);                          \
    A = fmaf(c2, a3, fmaf(c1, a2, pa));                        \
    if (PFLAG) { pf[(J)] = LDR(offp); offp += SB; }            \
    if (((J) & 15) == 15) RENF()                               \
  }

    for (int blk = 0; blk < 6; ++blk) {     // t = 1..192
#pragma unroll
      for (int j = 0; j < D; ++j) STEPF(j, true)
    }
#pragma unroll
    for (int j = 0; j < D; ++j) STEPF(j, j < 31)   // t = 193..224
#pragma unroll
    for (int j = 0; j < 31; ++j) STEPF(j, false)   // t = 225..255

    la_s[pairIdx][lane] = fmaxf((float)M2 * LN2F + logf(A), NEGV);
  } else {
    // ---------- backward: beta init at finals, consume p_511..p_256 ----------
    A = (lane == 2 * len - 1 || lane == 2 * len) ? 1.0f : 0.0f;
    F1 = 1.0f; F2m = skf2;
    offp = 511u * SB + rowoff;
#pragma unroll
    for (int j = 0; j < D; ++j) { pf[j] = LDR(offp); offp -= SB; }  // t=511..480

#define RENB() {                                               \
    int e2 = (int)(__float_as_uint(A) >> 23) - 127;            \
    A = ldexpf(A, -e2);                                        \
    int m2n = M2 + e2;                                         \
    int m2a = shl1i(m2n, 0);                                   \
    M2 = (A == 0.0f) ? m2a : m2n;                              \
    int s1 = shl1i(M2, 0), s2 = shl1i(s1, 0);                  \
    F1 = ldexpf(1.0f, iclamp126(s1 - M2));                     \
    F2m = skf2 * ldexpf(1.0f, iclamp126(s2 - M2));             \
  }
#define STEPB(J, PFLAG) {                                      \
    const float P = __expf(BPERM(pf[(J)]));                    \
    const float P1 = shl1f(P, 0.0f);                           \
    const float P2 = shl1f(P1, 0.0f);                          \
    const float c1 = F1 * P1, c2 = F2m * P2;                   \
    const float a1 = shl1f(A, 0.0f);                           \
    const float pa = P * A;                                    \
    const float a2 = shl1f(a1, 0.0f);                          \
    A = fmaf(c2, a2, fmaf(c1, a1, pa));                        \
    if (PFLAG) { pf[(J)] = LDR(offp); offp -= SB; }            \
    if (((J) & 15) == 15) RENB()                               \
  }

    for (int blk = 0; blk < 7; ++blk) {     // consume t = 511..288, prefetch t-32
#pragma unroll
      for (int j = 0; j < D; ++j) STEPB(j, true)
    }
#pragma unroll
    for (int j = 0; j < D; ++j) STEPB(j, false)    // t = 287..256
  }

  __syncthreads();

  if (bwd) {
    const float lb = fmaxf((float)M2 * LN2F + logf(A), NEGV);
    float v = (lane <= 50) ? la_s[pairIdx][lane] + lb : -2e30f;
    float m = v;
#pragma unroll
    for (int o = 32; o; o >>= 1) m = fmaxf(m, __shfl_xor(m, o));
    float s = __expf(v - m);
#pragma unroll
    for (int o = 32; o; o >>= 1) s += __shfl_xor(s, o);
    if (lane == 0) {
      const float ll = m + logf(s);
      float nll = -ll;
      if (!(nll <= 0.5e30f)) nll = 0.0f;   // zero_infinity (also NaN)
      const int dl = len > 1 ? len : 1;
      loss[b] = nll / (float)dl;
    }
  }
}

__global__ __launch_bounds__(256) void ctc_reduce_kernel(
    const float* __restrict__ loss, float* __restrict__ out) {
  float s = 0.f;
  for (int i = threadIdx.x; i < BB; i += 256) s += loss[i];
#pragma unroll
  for (int off = 32; off; off >>= 1) s += __shfl_down(s, off);
  __shared__ float sm[4];
  if ((threadIdx.x & 63) == 0) sm[threadIdx.x >> 6] = s;
  __syncthreads();
  if (threadIdx.x == 0) out[0] = (sm[0] + sm[1] + sm[2] + sm[3]) / (float)BB;
}

extern "C" void kernel_launch(void* const* d_in, const int* in_sizes, int n_in,
                              void* d_out, int out_size, void* d_ws, size_t ws_size,
                              hipStream_t stream) {
  const float* logp  = (const float*)d_in[0];
  const int* targets = (const int*)d_in[1];
  const int* tlen    = (const int*)d_in[2];
  float* out  = (float*)d_out;
  float* loss = (float*)d_ws;   // B floats of per-sample loss
  hipLaunchKernelGGL(ctc_fb_kernel, dim3(BB / 2), dim3(256), 0, stream,
                     logp, targets, tlen, loss);
  hipLaunchKernelGGL(ctc_reduce_kernel, dim3(1), dim3(256), 0, stream, loss, out);
}

// Round 6
// 31.907 us; speedup vs baseline: 1.0349x; 1.0349x over previous
//
#include <hip/hip_runtime.h>

// CTC loss forward (T=512, B=1024, C=63, S=25, L=51).
// One wave64 per batch element carrying BOTH directions:
//   fwd alpha chain (rows 1..255, shr1) and bwd beta chain (rows 511..256, shl1),
// linear domain with per-lane power-of-2 frames. 2 loads/step/wave doubles
// per-CU VMEM throughput vs round 4/5 (the measured ~8-10 B/cy/CU wall).
// Combine ll = log sum_s alpha_255[s]*beta_255[s] intra-wave.

#define TT 512
#define BB 1024
#define CC 63
#define SS 25
#define DP 24
#define NEGV (-1e30f)
#define LN2F 0.69314718055994531f

__device__ __forceinline__ float shr1f(float x, float fill) {  // lane s <- x[s-1]
  return __int_as_float(__builtin_amdgcn_update_dpp(
      __float_as_int(fill), __float_as_int(x), 0x138, 0xF, 0xF, false));
}
__device__ __forceinline__ int shr1i(int x, int fill) {
  return __builtin_amdgcn_update_dpp(fill, x, 0x138, 0xF, 0xF, false);
}
__device__ __forceinline__ float shl1f(float x, float fill) {  // lane s <- x[s+1]
  return __int_as_float(__builtin_amdgcn_update_dpp(
      __float_as_int(fill), __float_as_int(x), 0x130, 0xF, 0xF, false));
}
__device__ __forceinline__ int shl1i(int x, int fill) {
  return __builtin_amdgcn_update_dpp(fill, x, 0x130, 0xF, 0xF, false);
}
__device__ __forceinline__ int iclamp126(int d) {
  return d < -126 ? -126 : (d > 126 ? 126 : d);
}

__global__ __launch_bounds__(256) void ctc_fb_kernel(
    const float* __restrict__ logp,
    const int* __restrict__ targets,
    const int* __restrict__ tlen,
    float* __restrict__ loss) {
  const int lane = threadIdx.x & 63;
  const int wid = threadIdx.x >> 6;
  const int b = (blockIdx.x << 2) + wid;           // 4 waves/block, 1 batch/wave
  const int* tg = targets + b * SS;
  const int len = tlen[b];

  // ext[s]: even s -> blank(0); odd s -> tg[(s-1)/2]
  int e = 0;
  float skf = 0.0f;   // fwd: inflow s-2 -> s allowed
  float skf2 = 0.0f;  // bwd: inflow s+2 -> s allowed
  if (lane & 1) {
    const int i = lane >> 1;
    if (i < SS) {
      e = tg[i];
      skf = (i == 0 || e != tg[i - 1]) ? 1.0f : 0.0f;
      if (i + 1 < SS) skf2 = (tg[i + 1] != tg[i]) ? 1.0f : 0.0f;
    }
  }

  const unsigned SB = (unsigned)(BB * CC) * 4u;    // bytes per timestep row block
  const char* base = (const char*)logp;
  const unsigned off0 = (unsigned)(b * CC + e) * 4u;
#define LDR(O) (*(const float*)(base + (O)))

  // fwd state
  float Af = (lane <= 1) ? __expf(LDR(off0)) : 0.0f;
  int M2f = 0;
  float F1f = 1.0f, F2f = skf;
  // bwd state (beta_511 init at final states)
  float Ab = (lane == 2 * len - 1 || lane == 2 * len) ? 1.0f : 0.0f;
  int M2b = 0;
  float F1b = 1.0f, F2b = skf2;

  // rings: pfF[j] = row 1+j ; pfB[j] = row 511-j
  float pfF[DP], pfB[DP];
  unsigned offF = off0 + SB;
  unsigned offB = off0 + 511u * SB;
#pragma unroll
  for (int j = 0; j < DP; ++j) {
    pfF[j] = LDR(offF); offF += SB;
    pfB[j] = LDR(offB); offB -= SB;
  }
  // offF -> row 25 ; offB -> row 487

#define RENF() {                                               \
    int e2 = (int)(__float_as_uint(Af) >> 23) - 127;           \
    Af = ldexpf(Af, -e2);                                      \
    int m2n = M2f + e2;                                        \
    int m2a = shr1i(m2n, 0);                                   \
    M2f = (Af == 0.0f) ? m2a : m2n;                            \
    int s1 = shr1i(M2f, 0), s2 = shr1i(s1, 0);                 \
    F1f = ldexpf(1.0f, iclamp126(s1 - M2f));                   \
    F2f = skf * ldexpf(1.0f, iclamp126(s2 - M2f));             \
  }
#define RENB() {                                               \
    int e2 = (int)(__float_as_uint(Ab) >> 23) - 127;           \
    Ab = ldexpf(Ab, -e2);                                      \
    int m2n = M2b + e2;                                        \
    int m2a = shl1i(m2n, 0);                                   \
    M2b = (Ab == 0.0f) ? m2a : m2n;                            \
    int s1 = shl1i(M2b, 0), s2 = shl1i(s1, 0);                 \
    F1b = ldexpf(1.0f, iclamp126(s1 - M2b));                   \
    F2b = skf2 * ldexpf(1.0f, iclamp126(s2 - M2b));            \
  }
#define STEPF(J, PFLAG) {                                      \
    const float P = __expf(pfF[(J)]);                          \
    const float c1 = P * F1f, c2 = P * F2f;                    \
    const float x1 = shr1f(Af, 0.0f);                          \
    const float pa = P * Af;                                   \
    const float x2 = shr1f(x1, 0.0f);                          \
    Af = fmaf(c2, x2, fmaf(c1, x1, pa));                       \
    if (PFLAG) { pfF[(J)] = LDR(offF); offF += SB; }           \
  }
#define STEPB(J, PFLAG) {                                      \
    const float P = __expf(pfB[(J)]);                          \
    const float P1 = shl1f(P, 0.0f);                           \
    const float P2 = shl1f(P1, 0.0f);                          \
    const float c1 = F1b * P1, c2 = F2b * P2;                  \
    const float y1 = shl1f(Ab, 0.0f);                          \
    const float pb = P * Ab;                                   \
    const float y2 = shl1f(y1, 0.0f);                          \
    Ab = fmaf(c2, y2, fmaf(c1, y1, pb));                       \
    if (PFLAG) { pfB[(J)] = LDR(offB); offB -= SB; }           \
  }

  // peel k=0: bwd consumes row 511 (slot 0), refill with row 487
  STEPB(0, true)

  // main: k = 1 + 24*blk + j; fwd consumes row k (slot j),
  // bwd consumes row 511-k (slot (j+1)%24). Prefetch valid while k <= 231.
  for (int blk = 0; blk < 9; ++blk) {
#pragma unroll
    for (int j = 0; j < DP; ++j) {
      STEPF(j, true)
      STEPB((j + 1) % DP, true)
      if (j == 11 || j == 23) { RENF() RENB() }
    }
  }
  // blk 9: k = 217..240, prefetch iff j <= 14 (k <= 231)
#pragma unroll
  for (int j = 0; j < DP; ++j) {
    STEPF(j, j <= 14)
    STEPB((j + 1) % DP, j <= 14)
    if (j == 11 || j == 23) { RENF() RENB() }
  }
  // tail: k = 241..255 (15 steps), no prefetch
#pragma unroll
  for (int j = 0; j < 15; ++j) {
    STEPF(j, false)
    STEPB(j + 1, false)
    if (j == 11) { RENF() RENB() }
  }

  // combine: ll = log sum_{s<=50} alpha_255[s] * beta_255[s]
  const float laf = fmaxf((float)M2f * LN2F + logf(Af), NEGV);
  const float lab = fmaxf((float)M2b * LN2F + logf(Ab), NEGV);
  float v = (lane <= 50) ? laf + lab : -2e30f;
  float m = v;
#pragma unroll
  for (int o = 32; o; o >>= 1) m = fmaxf(m, __shfl_xor(m, o));
  float s = __expf(v - m);
#pragma unroll
  for (int o = 32; o; o >>= 1) s += __shfl_xor(s, o);
  if (lane == 0) {
    const float ll = m + logf(s);
    float nll = -ll;
    if (!(nll <= 0.5e30f)) nll = 0.0f;   // zero_infinity (also NaN)
    const int dl = len > 1 ? len : 1;
    loss[b] = nll / (float)dl;
  }
}

__global__ __launch_bounds__(256) void ctc_reduce_kernel(
    const float* __restrict__ loss, float* __restrict__ out) {
  float s = 0.f;
  for (int i = threadIdx.x; i < BB; i += 256) s += loss[i];
#pragma unroll
  for (int off = 32; off; off >>= 1) s += __shfl_down(s, off);
  __shared__ float sm[4];
  if ((threadIdx.x & 63) == 0) sm[threadIdx.x >> 6] = s;
  __syncthreads();
  if (threadIdx.x == 0) out[0] = (sm[0] + sm[1] + sm[2] + sm[3]) / (float)BB;
}

extern "C" void kernel_launch(void* const* d_in, const int* in_sizes, int n_in,
                              void* d_out, int out_size, void* d_ws, size_t ws_size,
                              hipStream_t stream) {
  const float* logp  = (const float*)d_in[0];
  const int* targets = (const int*)d_in[1];
  const int* tlen    = (const int*)d_in[2];
  float* out  = (float*)d_out;
  float* loss = (float*)d_ws;   // B floats of per-sample loss
  hipLaunchKernelGGL(ctc_fb_kernel, dim3(BB / 4), dim3(256), 0, stream,
                     logp, targets, tlen, loss);
  hipLaunchKernelGGL(ctc_reduce_kernel, dim3(1), dim3(256), 0, stream, loss, out);
}